// Round 7
// baseline (685.300 us; speedup 1.0000x reference)
//
#include <hip/hip_runtime.h>
#include <hip/hip_bf16.h>
#include <math.h>

// ---------------- problem constants ----------------
#define B_SZ   2
#define L_SZ   2048
#define DM     1024          // d_model
#define DI     2048          // d_inner
#define DS     16            // d_state
#define M_SZ   (B_SZ * L_SZ) // 4096 rows
#define N_XZ   (2 * DI)      // 4096
#define LDF    20            // uints per LDS row (32 bf16 + 8 pad) -- r8-proven
#define SEGS   32
#define SEGLEN 64            // L_SZ / SEGS
#define KZN    8             // gemm_bcf K-split factor

typedef short bf16x8 __attribute__((ext_vector_type(8)));
typedef float f32x4  __attribute__((ext_vector_type(4)));

__device__ __forceinline__ unsigned short rne16(float f) {
  unsigned int u = __builtin_bit_cast(unsigned int, f);
  u += 0x7FFFu + ((u >> 16) & 1u);
  return (unsigned short)(u >> 16);
}
__device__ __forceinline__ float frombf(unsigned short h) {
  unsigned int u = ((unsigned int)h) << 16;
  return __builtin_bit_cast(float, u);
}

// ---------------- x -> (x_hi, x_lo) bf16 split ----------------
__global__ __launch_bounds__(256) void convert_x(
    const float* __restrict__ x, unsigned short* __restrict__ xh,
    unsigned short* __restrict__ xl) {
  int i = (blockIdx.x * 256 + threadIdx.x) * 4;
  float4 v = *(const float4*)(x + i);
  unsigned short h0 = rne16(v.x), h1 = rne16(v.y), h2 = rne16(v.z), h3 = rne16(v.w);
  *(ushort4*)(xh + i) = make_ushort4(h0, h1, h2, h3);
  *(ushort4*)(xl + i) = make_ushort4(rne16(v.x - frombf(h0)), rne16(v.y - frombf(h1)),
                                     rne16(v.z - frombf(h2)), rne16(v.w - frombf(h3)));
}

// ---------------- W (RxC fp32) -> W^T (CxR) bf16 hi (+lo) ----------------
__global__ __launch_bounds__(256) void transpose_w(
    const float* __restrict__ in, int R, int C,
    unsigned short* __restrict__ oh, unsigned short* __restrict__ ol) {
  __shared__ float T[64][65];
  const int tid = threadIdx.x;
  const int c0 = blockIdx.x * 64, r0 = blockIdx.y * 64;
  const int cc = tid & 63, rq = tid >> 6;
  #pragma unroll
  for (int i = 0; i < 16; ++i) {
    int r = rq * 16 + i;
    T[r][cc] = in[(size_t)(r0 + r) * C + c0 + cc];
  }
  __syncthreads();
  #pragma unroll
  for (int i = 0; i < 16; ++i) {
    int c = rq * 16 + i;
    float v = T[cc][c];
    size_t o = (size_t)(c0 + c) * R + r0 + cc;
    unsigned short h = rne16(v);
    oh[o] = h;
    if (ol) ol[o] = rne16(v - frombf(h));
  }
}

// ---------------- bf16 MFMA GEMM (optionally bf16x3), pre-converted inputs ----------------
// EXACT r8-proven body (LDF=20, launch_bounds (256, X3?3:4)); only the epilogue
// output path is parameterized (OUTBF16).
template<int BN, bool X3, bool OUTBF16>
__global__ __launch_bounds__(256, X3 ? 3 : 4) void gemm_t(
    const unsigned short* __restrict__ Ah, const unsigned short* __restrict__ Al, int lda,
    const unsigned short* __restrict__ Bh, const unsigned short* __restrict__ Bl, int ldb,
    const float* __restrict__ bias, float* __restrict__ Cf,
    unsigned short* __restrict__ Cz, int ldc, int K) {
  constexpr int WN  = BN / 2;      // wave col extent
  constexpr int FJ  = BN / 32;     // col frags per wave
  constexpr int BCH = BN / 64;     // B staging chunks per thread
  __shared__ unsigned int AhS[128 * LDF];
  __shared__ unsigned int BhS[BN * LDF];
  __shared__ unsigned int AlS[X3 ? 128 * LDF : 4];
  __shared__ unsigned int BlS[X3 ? BN * LDF : 4];
  const int tid  = threadIdx.x;
  const int lane = tid & 63, wave = tid >> 6;
  const int wr = wave >> 1, wc = wave & 1;
  const int lm = lane & 15, lq = lane >> 4;
  const int row0 = blockIdx.y * 128, col0 = blockIdx.x * BN;

  f32x4 acc[4][FJ];
  #pragma unroll
  for (int i = 0; i < 4; ++i)
    #pragma unroll
    for (int j = 0; j < FJ; ++j) acc[i][j] = (f32x4){0.f, 0.f, 0.f, 0.f};

  for (int k0 = 0; k0 < K; k0 += 32) {
    __syncthreads();
    // A tiles: 128 rows x 32 k, uint4 (8 bf16) per chunk
    #pragma unroll
    for (int i = 0; i < 2; ++i) {
      int idx = tid + i * 256, r = idx >> 2, q = idx & 3;
      size_t go = (size_t)(row0 + r) * lda + k0 + q * 8;
      *(uint4*)&AhS[r * LDF + q * 4] = *(const uint4*)(Ah + go);
      if constexpr (X3)
        *(uint4*)&AlS[r * LDF + q * 4] = *(const uint4*)(Al + go);
    }
    // B tiles: BN rows (n) x 32 k
    #pragma unroll
    for (int i = 0; i < BCH; ++i) {
      int idx = tid + i * 256, r = idx >> 2, q = idx & 3;
      size_t go = (size_t)(col0 + r) * ldb + k0 + q * 8;
      *(uint4*)&BhS[r * LDF + q * 4] = *(const uint4*)(Bh + go);
      if constexpr (X3)
        *(uint4*)&BlS[r * LDF + q * 4] = *(const uint4*)(Bl + go);
    }
    __syncthreads();
    bf16x8 bh[FJ], bl[FJ];
    #pragma unroll
    for (int j = 0; j < FJ; ++j) {
      bh[j] = *(const bf16x8*)&BhS[(wc * WN + j * 16 + lm) * LDF + lq * 4];
      if constexpr (X3)
        bl[j] = *(const bf16x8*)&BlS[(wc * WN + j * 16 + lm) * LDF + lq * 4];
    }
    #pragma unroll
    for (int i = 0; i < 4; ++i) {
      bf16x8 ah = *(const bf16x8*)&AhS[(wr * 64 + i * 16 + lm) * LDF + lq * 4];
      bf16x8 al;
      if constexpr (X3)
        al = *(const bf16x8*)&AlS[(wr * 64 + i * 16 + lm) * LDF + lq * 4];
      #pragma unroll
      for (int j = 0; j < FJ; ++j) {
        acc[i][j] = __builtin_amdgcn_mfma_f32_16x16x32_bf16(ah, bh[j], acc[i][j], 0, 0, 0);
        if constexpr (X3) {
          acc[i][j] = __builtin_amdgcn_mfma_f32_16x16x32_bf16(ah, bl[j], acc[i][j], 0, 0, 0);
          acc[i][j] = __builtin_amdgcn_mfma_f32_16x16x32_bf16(al, bh[j], acc[i][j], 0, 0, 0);
        }
      }
    }
  }
  // epilogue: C/D layout col=lane&15, row=(lane>>4)*4+reg
  #pragma unroll
  for (int i = 0; i < 4; ++i) {
    #pragma unroll
    for (int j = 0; j < FJ; ++j) {
      int c = col0 + wc * WN + j * 16 + lm;
      float bs = bias[c];
      #pragma unroll
      for (int k = 0; k < 4; ++k) {
        int r = row0 + wr * 64 + i * 16 + lq * 4 + k;
        float v = acc[i][j][k] + bs;
        if constexpr (OUTBF16) Cz[(size_t)r * ldc + c] = rne16(v);
        else                   Cf[(size_t)r * ldc + c] = v;
      }
    }
  }
}

// ---------------- depthwise causal conv (k=4, left pad 3) + SiLU ----------------
__global__ __launch_bounds__(256) void conv_silu_kernel(
    const float* __restrict__ xi, const float* __restrict__ Wc,
    const float* __restrict__ bc, float* __restrict__ xc) {
  int idx = blockIdx.x * blockDim.x + threadIdx.x;   // over M_SZ*DI
  if (idx >= M_SZ * DI) return;
  int d  = idx & (DI - 1);
  int bl = idx >> 11;            // row (b*L + l)
  int l  = bl & (L_SZ - 1);
  float4 w = ((const float4*)Wc)[d];
  const float* base = xi + (size_t)bl * DI + d;
  float s = bc[d] + base[0] * w.w;
  if (l >= 1) s = fmaf(base[-DI],     w.z, s);
  if (l >= 2) s = fmaf(base[-2 * DI], w.y, s);
  if (l >= 3) s = fmaf(base[-3 * DI], w.x, s);
  float sig = 1.f / (1.f + expf(-s));
  xc[idx] = s * sig;
}

// ---------------- W_B/W_C -> WbcT[64][2048] bf16 hi/lo (interleaved cols, zero-padded) ----------------
__global__ __launch_bounds__(256) void prep_wbc(
    const float* __restrict__ WB, const float* __restrict__ WC,
    unsigned short* __restrict__ Wh, unsigned short* __restrict__ Wl) {
  int idx = blockIdx.x * 256 + threadIdx.x;   // 64*2048
  int c = idx >> 11, k = idx & 2047;
  float v = 0.f;
  if (c < 32) {
    const float* W = (c & 1) ? WC : WB;
    v = W[k * DS + (c >> 1)];
  }
  unsigned short h = rne16(v);
  Wh[idx] = h;
  Wl[idx] = rne16(v - frombf(h));
}

// ---------------- MFMA B/C projection (r6-proven): parts[kz] = xc @ WbcT^T ----------------
__global__ __launch_bounds__(256, 3) void gemm_bcf(
    const float* __restrict__ Af, int lda,
    const unsigned short* __restrict__ Bh, const unsigned short* __restrict__ Bl, int ldb,
    float* __restrict__ parts, int ldc, int Kslice) {
  __shared__ unsigned int AhS[128 * LDF];
  __shared__ unsigned int AlS[128 * LDF];
  __shared__ unsigned int BhS[64 * LDF];
  __shared__ unsigned int BlS[64 * LDF];
  const int tid  = threadIdx.x;
  const int lane = tid & 63, wave = tid >> 6;
  const int wr = wave >> 1, wc = wave & 1;
  const int lm = lane & 15, lq = lane >> 4;
  const int row0 = blockIdx.y * 128;
  const int kbase = blockIdx.x * Kslice;
  float* Cp = parts + (size_t)blockIdx.x * M_SZ * 64;

  f32x4 acc[4][2];
  #pragma unroll
  for (int i = 0; i < 4; ++i)
    #pragma unroll
    for (int j = 0; j < 2; ++j) acc[i][j] = (f32x4){0.f, 0.f, 0.f, 0.f};

  for (int k0 = kbase; k0 < kbase + Kslice; k0 += 32) {
    __syncthreads();
    // A: 128 rows x 32 k fp32 -> hi/lo bf16 in LDS
    #pragma unroll
    for (int i = 0; i < 4; ++i) {
      int idx = tid + i * 256, r = idx >> 3, q = idx & 7;
      float4 v = *(const float4*)(Af + (size_t)(row0 + r) * lda + k0 + q * 4);
      unsigned short h0 = rne16(v.x), h1 = rne16(v.y), h2 = rne16(v.z), h3 = rne16(v.w);
      AhS[r * LDF + q * 2]     = (unsigned)h0 | ((unsigned)h1 << 16);
      AhS[r * LDF + q * 2 + 1] = (unsigned)h2 | ((unsigned)h3 << 16);
      unsigned short l0 = rne16(v.x - frombf(h0)), l1 = rne16(v.y - frombf(h1));
      unsigned short l2 = rne16(v.z - frombf(h2)), l3 = rne16(v.w - frombf(h3));
      AlS[r * LDF + q * 2]     = (unsigned)l0 | ((unsigned)l1 << 16);
      AlS[r * LDF + q * 2 + 1] = (unsigned)l2 | ((unsigned)l3 << 16);
    }
    // B: 64 rows x 32 k bf16 (hi+lo)
    {
      int r = tid >> 2, q = tid & 3;
      size_t go = (size_t)r * ldb + k0 + q * 8;
      *(uint4*)&BhS[r * LDF + q * 4] = *(const uint4*)(Bh + go);
      *(uint4*)&BlS[r * LDF + q * 4] = *(const uint4*)(Bl + go);
    }
    __syncthreads();
    bf16x8 bh[2], bl[2];
    #pragma unroll
    for (int j = 0; j < 2; ++j) {
      bh[j] = *(const bf16x8*)&BhS[(wc * 32 + j * 16 + lm) * LDF + lq * 4];
      bl[j] = *(const bf16x8*)&BlS[(wc * 32 + j * 16 + lm) * LDF + lq * 4];
    }
    #pragma unroll
    for (int i = 0; i < 4; ++i) {
      bf16x8 ah = *(const bf16x8*)&AhS[(wr * 64 + i * 16 + lm) * LDF + lq * 4];
      bf16x8 al = *(const bf16x8*)&AlS[(wr * 64 + i * 16 + lm) * LDF + lq * 4];
      #pragma unroll
      for (int j = 0; j < 2; ++j) {
        acc[i][j] = __builtin_amdgcn_mfma_f32_16x16x32_bf16(ah, bh[j], acc[i][j], 0, 0, 0);
        acc[i][j] = __builtin_amdgcn_mfma_f32_16x16x32_bf16(ah, bl[j], acc[i][j], 0, 0, 0);
        acc[i][j] = __builtin_amdgcn_mfma_f32_16x16x32_bf16(al, bh[j], acc[i][j], 0, 0, 0);
      }
    }
  }
  #pragma unroll
  for (int i = 0; i < 4; ++i) {
    #pragma unroll
    for (int j = 0; j < 2; ++j) {
      int c = wc * 32 + j * 16 + lm;
      #pragma unroll
      for (int k = 0; k < 4; ++k) {
        int r = row0 + wr * 64 + i * 16 + lq * 4 + k;
        Cp[(size_t)r * ldc + c] = acc[i][j][k];
      }
    }
  }
}

// ---------------- sum K-split partials + bias -> BCm2 (stride 64) + Bt (s-major) ----------------
// Bt[(b*DS+s)*L_SZ + t]: per-(s) contiguous-in-t B rows for scan_maps float4 loads.
__global__ __launch_bounds__(256) void prep_bc_sum(
    const float* __restrict__ parts,
    const float* __restrict__ bB, const float* __restrict__ bC,
    float* __restrict__ BCm2, float* __restrict__ Bt) {
  int idx = blockIdx.x * 256 + threadIdx.x;   // M_SZ * 32
  int row = idx >> 5, c = idx & 31;
  float s = 0.f;
  #pragma unroll
  for (int kz = 0; kz < KZN; ++kz)
    s += parts[(size_t)kz * M_SZ * 64 + (size_t)row * 64 + c];
  s += (c & 1) ? bC[c >> 1] : bB[c >> 1];
  BCm2[(size_t)row * 64 + c] = s;
  if (!(c & 1)) {
    int b = row >> 11, t = row & 2047;
    Bt[((size_t)b * DS + (c >> 1)) * L_SZ + t] = s;
  }
}

// ---------------- selective scan ----------------
__device__ __forceinline__ float clampA(float a) {
  return fminf(fmaxf(a, -10.f), 2.f);
}

// ---- pass 1 v3: parallel composed clamped-affine maps ----
// r6 post-mortem: serial pass1 is latency-walled at 1 wave/SIMD (VGPR=64 shows
// the compiler collapsed the r5 register pipeline; 77 cyc/step). The recurrence
// h <- clamp(A h + u, -100, 100) is CLOSED under composition: maps of the form
// h -> clamp(a h + b, lo, hi) compose as (A<0 per element):
//   a' = A*a;  b' = fma(A, b, u);  lo' = clamp(fma(A, hi, u));  hi' = clamp(fma(A, lo, u))
// and lo/hi ARE the saturated trajectories, so any trajectory that clips is
// reproduced BITWISE by map evaluation; only the unsaturated nonzero-h0 affine
// eval rounds differently (~1e-5 abs, further decayed by pass2's serial rerun).
// scan_maps: 65536 chains x 32 segments compose 64-step maps fully in parallel
// (2M tasks, full chip), then 16 threads/block apply the 32 maps serially (31
// evals of fma+med3) and write hseg exactly as pass2 expects.
// a/b may overflow to +-inf when |A|>1 (safe through mul/fma: never NaN since
// A!=0 and u finite); sanitized once at segment end via med3(+-1e30).
#define LOADCH(xv, bv, base) { \
  _Pragma("unroll") for (int j = 0; j < 16; ++j) xv[j] = px[(base + j) * DI]; \
  _Pragma("unroll") for (int q = 0; q < 4; ++q) { \
    float4 t4 = *(const float4*)(pB + base + q * 4); \
    bv[q * 4] = t4.x; bv[q * 4 + 1] = t4.y; bv[q * 4 + 2] = t4.z; bv[q * 4 + 3] = t4.w; } }

#define MSTEP(u) { \
  float uu = (u); \
  float nb = fmaf(A, bb, uu); \
  float nl = __builtin_amdgcn_fmed3f(fmaf(A, hi, uu), -100.f, 100.f); \
  float nh = __builtin_amdgcn_fmed3f(fmaf(A, lo, uu), -100.f, 100.f); \
  a *= A; bb = nb; lo = nl; hi = nh; }

__global__ __launch_bounds__(512, 1) void scan_maps(
    const float* __restrict__ xc, const float* __restrict__ Bt,
    const float* __restrict__ A_log, float* __restrict__ hseg) {
  // XCD-chunked chain swizzle (xcd = bid%8 heuristic): consecutive-d blocks
  // colocate per XCD so each 16-d-wide x cache line is HBM-fetched once.
  const int bid   = blockIdx.x;                    // 0..4095
  const int chain = (bid & 7) * 512 + (bid >> 3);  // bijective
  const int b = chain >> 11, d = chain & 2047;
  const int tid = threadIdx.x;                     // 512 = 32 segs x 16 states
  const int g = tid & 31;                          // segment
  const int s = tid >> 5;                          // state

  const float A = -expf(clampA(A_log[d * DS + s]));

  const float* px = xc + ((size_t)b * L_SZ + g * SEGLEN) * DI + d;
  const float* pB = Bt + ((size_t)b * DS + s) * L_SZ + g * SEGLEN;

  float xa[16], ba[16], xn[16], bn[16];
  LOADCH(xa, ba, 0)
  LOADCH(xn, bn, 16)

  // init with step 0's element: h -> clamp(A h + u0, -100, 100)
  float a = A, bb = xa[0] * ba[0], lo = -100.f, hi = 100.f;
  #pragma unroll
  for (int j = 1; j < 16; ++j) MSTEP(xa[j] * ba[j])
  LOADCH(xa, ba, 32)
  #pragma unroll
  for (int j = 0; j < 16; ++j) MSTEP(xn[j] * bn[j])
  LOADCH(xn, bn, 48)
  #pragma unroll
  for (int j = 0; j < 16; ++j) MSTEP(xa[j] * ba[j])
  #pragma unroll
  for (int j = 0; j < 16; ++j) MSTEP(xn[j] * bn[j])

  // sanitize overflow (med3 maps +-inf into +-1e30; products then stay finite)
  a  = __builtin_amdgcn_fmed3f(a,  -1e30f, 1e30f);
  bb = __builtin_amdgcn_fmed3f(bb, -1e30f, 1e30f);

  __shared__ float LM[SEGS][DS][4];
  LM[g][s][0] = a; LM[g][s][1] = bb; LM[g][s][2] = lo; LM[g][s][3] = hi;
  __syncthreads();

  // middle scan: 16 threads walk the 32 maps serially, emit 31 boundary states
  if (tid < DS) {
    float h = 0.f;
    #pragma unroll
    for (int k = 0; k < SEGS - 1; ++k) {
      float4 m = *(const float4*)&LM[k][tid][0];
      h = __builtin_amdgcn_fmed3f(fmaf(m.x, h, m.y), m.z, m.w);
      hseg[(((size_t)b * (SEGS - 1) + k) * DI + d) * DS + tid] = h;
    }
  }
}

// ---- pass 2: channel-major, h[16]/A[16] in registers, zero cross-lane (r4/r6-proven) ----
__global__ __launch_bounds__(256, 2) void scan_pass2(
    const float* __restrict__ xc, const float* __restrict__ BCm2,
    const unsigned short* __restrict__ zb,
    const float* __restrict__ A_log, const float* __restrict__ Dv,
    const float* __restrict__ hseg, unsigned short* __restrict__ yg) {
  const int b   = blockIdx.y >> 5;        // SEGS = 32
  const int seg = blockIdx.y & 31;
  const int d   = blockIdx.x * 256 + threadIdx.x;

  float A[16], h[16];
  #pragma unroll
  for (int q = 0; q < 4; ++q) {
    float4 al = *(const float4*)(A_log + d * DS + q * 4);
    A[q * 4 + 0] = -expf(clampA(al.x));
    A[q * 4 + 1] = -expf(clampA(al.y));
    A[q * 4 + 2] = -expf(clampA(al.z));
    A[q * 4 + 3] = -expf(clampA(al.w));
  }
  const float Dr = Dv[d];
  if (seg == 0) {
    #pragma unroll
    for (int s = 0; s < 16; ++s) h[s] = 0.f;
  } else {
    const float* hp = hseg + (((size_t)b * (SEGS - 1) + seg - 1) * DI + d) * DS;
    #pragma unroll
    for (int q = 0; q < 4; ++q) {
      float4 hv = *(const float4*)(hp + q * 4);
      h[q * 4 + 0] = hv.x; h[q * 4 + 1] = hv.y;
      h[q * 4 + 2] = hv.z; h[q * 4 + 3] = hv.w;
    }
  }

  const int rbase = b * L_SZ + seg * SEGLEN;
  const float*          px  = xc  + (size_t)rbase * DI + d;
  const unsigned short* pz  = zb  + (size_t)rbase * DI + d;
  unsigned short*       py  = yg  + (size_t)rbase * DI + d;
  const float*          pbc = BCm2 + (size_t)rbase * 64;

  #pragma unroll 2
  for (int t = 0; t < SEGLEN; ++t) {
    const float x = px[t * DI];
    const float* bc = pbc + t * 64;   // wave-uniform address
    float y = Dr * x;
    #pragma unroll
    for (int s = 0; s < 16; ++s) {
      h[s] = __builtin_amdgcn_fmed3f(fmaf(h[s], A[s], x * bc[s * 2]), -100.f, 100.f);
      y = fmaf(h[s], bc[s * 2 + 1], y);
    }
    y = __builtin_amdgcn_fmed3f(y, -100.f, 100.f);
    const float zf = frombf(pz[t * DI]);
    py[t * DI] = rne16(y * (1.f / (1.f + expf(-zf))));
  }
}

// ---------------- launch ----------------
// ws layout (bytes), peak 88.6 MB:
//   [0,        16777216)  yg bf16 (after conv; region was xi fp32 GEMM1 out)
//   [16777216, 25165824)  parts fp32 (gemm_bcf partials, 8 MB; dead after
//                          prep_bc_sum) -- then hseg fp32 [16777216, 24903680)
//   [25165824, 26214400)  BCm2 fp32 stride-64 {B,C} (1 MB)
//   [26214400, 26476544)  Bt fp32 s-major B (256 KB)
//   [0,        33554432)  xi fp32 before conv (GEMM1 out, conv in)
//   [33554432, 50331648)  z bf16
//   [50331648, 83886080)  xc fp32 (conv out); BEFORE conv hosts xh/xl/WhT/WlT
//   [83886080, 84410368)  WbcT bf16 hi+lo (512 KB)
//   [84410368, 88604672)  WoutT bf16
extern "C" void kernel_launch(void* const* d_in, const int* in_sizes, int n_in,
                              void* d_out, int out_size, void* d_ws, size_t ws_size,
                              hipStream_t stream) {
  const float* x      = (const float*)d_in[0];
  const float* W_in   = (const float*)d_in[1];
  const float* b_in   = (const float*)d_in[2];
  const float* W_conv = (const float*)d_in[3];
  const float* b_conv = (const float*)d_in[4];
  const float* A_log  = (const float*)d_in[5];
  const float* Dv     = (const float*)d_in[6];
  const float* W_B    = (const float*)d_in[7];
  const float* b_B    = (const float*)d_in[8];
  const float* W_C    = (const float*)d_in[9];
  const float* b_C    = (const float*)d_in[10];
  const float* W_out  = (const float*)d_in[11];
  const float* b_out  = (const float*)d_in[12];
  float* out = (float*)d_out;

  char* w = (char*)d_ws;
  float*          xi    = (float*)(w + 0);
  unsigned short* yg    = (unsigned short*)(w + 0);          // reuse after conv
  float*          parts = (float*)(w + 16777216);            // dead-xi zone
  float*          hseg  = (float*)(w + 16777216);            // after parts die
  float*          BCm2  = (float*)(w + 25165824);
  float*          Bt    = (float*)(w + 26214400);
  unsigned short* zb    = (unsigned short*)(w + 33554432);
  float*          xc    = (float*)(w + 50331648);
  unsigned short* xh    = (unsigned short*)(w + 50331648);   // pre-conv phase
  unsigned short* xl    = (unsigned short*)(w + 58720256);
  unsigned short* WhT   = (unsigned short*)(w + 67108864);
  unsigned short* WlT   = (unsigned short*)(w + 75497472);
  unsigned short* WbcTh = (unsigned short*)(w + 83886080);
  unsigned short* WbcTl = (unsigned short*)(w + 84148224);
  unsigned short* WoT   = (unsigned short*)(w + 84410368);

  // 0a) x -> xh/xl
  convert_x<<<M_SZ * DM / 1024, 256, 0, stream>>>(x, xh, xl);
  // 0b) W_in (DM x N_XZ) -> WhT/WlT (N_XZ x DM)
  transpose_w<<<dim3(N_XZ / 64, DM / 64), 256, 0, stream>>>(W_in, DM, N_XZ, WhT, WlT);
  // 0c) W_out (DI x DM) -> WoT (DM x DI), hi only (post-scan path)
  transpose_w<<<dim3(DM / 64, DI / 64), 256, 0, stream>>>(W_out, DI, DM, WoT, nullptr);
  // 0d) W_B/W_C -> WbcT hi/lo
  prep_wbc<<<64 * 2048 / 256, 256, 0, stream>>>(W_B, W_C, WbcTh, WbcTl);

  // 1a) xi = x @ W_in[:, :DI] + b_in[:DI]  -- bf16x3 (scan-sensitive), fp32 out
  gemm_t<128, true, false><<<dim3(DI / 128, M_SZ / 128), 256, 0, stream>>>(
      xh, xl, DM, WhT, WlT, DM, b_in, xi, nullptr, DI, DM);

  // 1b) z = x @ W_in[:, DI:] + b_in[DI:]  -- plain bf16 (gate path), bf16 out
  gemm_t<128, false, true><<<dim3(DI / 128, M_SZ / 128), 256, 0, stream>>>(
      xh, nullptr, DM, WhT + (size_t)DI * DM, nullptr, DM,
      b_in + DI, nullptr, zb, DI, DM);

  // 2) xc = silu(causal_dwconv(xi) + b_conv)
  conv_silu_kernel<<<M_SZ * DI / 256, 256, 0, stream>>>(xi, W_conv, b_conv, xc);

  // 3a) B/C projection partials via MFMA (K-split 8, full chip)
  gemm_bcf<<<dim3(KZN, M_SZ / 128), 256, 0, stream>>>(
      xc, DI, WbcTh, WbcTl, DI, parts, 64, DI / KZN);
  // 3b) sum partials + bias -> BCm2 + Bt
  prep_bc_sum<<<M_SZ * 32 / 256, 256, 0, stream>>>(parts, b_B, b_C, BCm2, Bt);

  // 4a) pass1 v3: parallel composed clamped-affine maps -> 31 boundary states
  scan_maps<<<B_SZ * DI, 512, 0, stream>>>(xc, Bt, A_log, hseg);

  // 4b) pass2: 32 parallel 64-step segments -> yg bf16
  scan_pass2<<<dim3(DI / 256, B_SZ * SEGS), 256, 0, stream>>>(
      xc, BCm2, zb, A_log, Dv, hseg, yg);

  // 5) out = yg @ W_out + b_out, pure bf16 MFMA (BN=64)
  gemm_t<64, false, false><<<dim3(DM / 64, M_SZ / 128), 256, 0, stream>>>(
      yg, nullptr, DI, WoT, nullptr, DI, b_out, out, nullptr, DM, DI);
}

// Round 8
// 367.439 us; speedup vs baseline: 1.8651x; 1.8651x over previous
//
#include <hip/hip_runtime.h>
#include <hip/hip_bf16.h>
#include <math.h>

// ---------------- problem constants ----------------
#define B_SZ   2
#define L_SZ   2048
#define DM     1024          // d_model
#define DI     2048          // d_inner
#define DS     16            // d_state
#define M_SZ   (B_SZ * L_SZ) // 4096 rows
#define N_XZ   (2 * DI)      // 4096
#define LDF    20            // uints per LDS row (32 bf16 + 8 pad) -- r8-proven
#define SEGS   32
#define SEGLEN 64            // L_SZ / SEGS
#define KZN    8             // gemm_bcf K-split factor

typedef short bf16x8 __attribute__((ext_vector_type(8)));
typedef float f32x4  __attribute__((ext_vector_type(4)));

__device__ __forceinline__ unsigned short rne16(float f) {
  unsigned int u = __builtin_bit_cast(unsigned int, f);
  u += 0x7FFFu + ((u >> 16) & 1u);
  return (unsigned short)(u >> 16);
}
__device__ __forceinline__ float frombf(unsigned short h) {
  unsigned int u = ((unsigned int)h) << 16;
  return __builtin_bit_cast(float, u);
}

// ---------------- x -> (x_hi, x_lo) bf16 split ----------------
__global__ __launch_bounds__(256) void convert_x(
    const float* __restrict__ x, unsigned short* __restrict__ xh,
    unsigned short* __restrict__ xl) {
  int i = (blockIdx.x * 256 + threadIdx.x) * 4;
  float4 v = *(const float4*)(x + i);
  unsigned short h0 = rne16(v.x), h1 = rne16(v.y), h2 = rne16(v.z), h3 = rne16(v.w);
  *(ushort4*)(xh + i) = make_ushort4(h0, h1, h2, h3);
  *(ushort4*)(xl + i) = make_ushort4(rne16(v.x - frombf(h0)), rne16(v.y - frombf(h1)),
                                     rne16(v.z - frombf(h2)), rne16(v.w - frombf(h3)));
}

// ---------------- W (RxC fp32) -> W^T (CxR) bf16 hi (+lo) ----------------
__global__ __launch_bounds__(256) void transpose_w(
    const float* __restrict__ in, int R, int C,
    unsigned short* __restrict__ oh, unsigned short* __restrict__ ol) {
  __shared__ float T[64][65];
  const int tid = threadIdx.x;
  const int c0 = blockIdx.x * 64, r0 = blockIdx.y * 64;
  const int cc = tid & 63, rq = tid >> 6;
  #pragma unroll
  for (int i = 0; i < 16; ++i) {
    int r = rq * 16 + i;
    T[r][cc] = in[(size_t)(r0 + r) * C + c0 + cc];
  }
  __syncthreads();
  #pragma unroll
  for (int i = 0; i < 16; ++i) {
    int c = rq * 16 + i;
    float v = T[cc][c];
    size_t o = (size_t)(c0 + c) * R + r0 + cc;
    unsigned short h = rne16(v);
    oh[o] = h;
    if (ol) ol[o] = rne16(v - frombf(h));
  }
}

// ---------------- bf16 MFMA GEMM (optionally bf16x3), pre-converted inputs ----------------
// EXACT r8-proven body (LDF=20, launch_bounds (256, X3?3:4)); only the epilogue
// output path is parameterized (OUTBF16).
template<int BN, bool X3, bool OUTBF16>
__global__ __launch_bounds__(256, X3 ? 3 : 4) void gemm_t(
    const unsigned short* __restrict__ Ah, const unsigned short* __restrict__ Al, int lda,
    const unsigned short* __restrict__ Bh, const unsigned short* __restrict__ Bl, int ldb,
    const float* __restrict__ bias, float* __restrict__ Cf,
    unsigned short* __restrict__ Cz, int ldc, int K) {
  constexpr int WN  = BN / 2;      // wave col extent
  constexpr int FJ  = BN / 32;     // col frags per wave
  constexpr int BCH = BN / 64;     // B staging chunks per thread
  __shared__ unsigned int AhS[128 * LDF];
  __shared__ unsigned int BhS[BN * LDF];
  __shared__ unsigned int AlS[X3 ? 128 * LDF : 4];
  __shared__ unsigned int BlS[X3 ? BN * LDF : 4];
  const int tid  = threadIdx.x;
  const int lane = tid & 63, wave = tid >> 6;
  const int wr = wave >> 1, wc = wave & 1;
  const int lm = lane & 15, lq = lane >> 4;
  const int row0 = blockIdx.y * 128, col0 = blockIdx.x * BN;

  f32x4 acc[4][FJ];
  #pragma unroll
  for (int i = 0; i < 4; ++i)
    #pragma unroll
    for (int j = 0; j < FJ; ++j) acc[i][j] = (f32x4){0.f, 0.f, 0.f, 0.f};

  for (int k0 = 0; k0 < K; k0 += 32) {
    __syncthreads();
    // A tiles: 128 rows x 32 k, uint4 (8 bf16) per chunk
    #pragma unroll
    for (int i = 0; i < 2; ++i) {
      int idx = tid + i * 256, r = idx >> 2, q = idx & 3;
      size_t go = (size_t)(row0 + r) * lda + k0 + q * 8;
      *(uint4*)&AhS[r * LDF + q * 4] = *(const uint4*)(Ah + go);
      if constexpr (X3)
        *(uint4*)&AlS[r * LDF + q * 4] = *(const uint4*)(Al + go);
    }
    // B tiles: BN rows (n) x 32 k
    #pragma unroll
    for (int i = 0; i < BCH; ++i) {
      int idx = tid + i * 256, r = idx >> 2, q = idx & 3;
      size_t go = (size_t)(col0 + r) * ldb + k0 + q * 8;
      *(uint4*)&BhS[r * LDF + q * 4] = *(const uint4*)(Bh + go);
      if constexpr (X3)
        *(uint4*)&BlS[r * LDF + q * 4] = *(const uint4*)(Bl + go);
    }
    __syncthreads();
    bf16x8 bh[FJ], bl[FJ];
    #pragma unroll
    for (int j = 0; j < FJ; ++j) {
      bh[j] = *(const bf16x8*)&BhS[(wc * WN + j * 16 + lm) * LDF + lq * 4];
      if constexpr (X3)
        bl[j] = *(const bf16x8*)&BlS[(wc * WN + j * 16 + lm) * LDF + lq * 4];
    }
    #pragma unroll
    for (int i = 0; i < 4; ++i) {
      bf16x8 ah = *(const bf16x8*)&AhS[(wr * 64 + i * 16 + lm) * LDF + lq * 4];
      bf16x8 al;
      if constexpr (X3)
        al = *(const bf16x8*)&AlS[(wr * 64 + i * 16 + lm) * LDF + lq * 4];
      #pragma unroll
      for (int j = 0; j < FJ; ++j) {
        acc[i][j] = __builtin_amdgcn_mfma_f32_16x16x32_bf16(ah, bh[j], acc[i][j], 0, 0, 0);
        if constexpr (X3) {
          acc[i][j] = __builtin_amdgcn_mfma_f32_16x16x32_bf16(ah, bl[j], acc[i][j], 0, 0, 0);
          acc[i][j] = __builtin_amdgcn_mfma_f32_16x16x32_bf16(al, bh[j], acc[i][j], 0, 0, 0);
        }
      }
    }
  }
  // epilogue: C/D layout col=lane&15, row=(lane>>4)*4+reg
  #pragma unroll
  for (int i = 0; i < 4; ++i) {
    #pragma unroll
    for (int j = 0; j < FJ; ++j) {
      int c = col0 + wc * WN + j * 16 + lm;
      float bs = bias[c];
      #pragma unroll
      for (int k = 0; k < 4; ++k) {
        int r = row0 + wr * 64 + i * 16 + lq * 4 + k;
        float v = acc[i][j][k] + bs;
        if constexpr (OUTBF16) Cz[(size_t)r * ldc + c] = rne16(v);
        else                   Cf[(size_t)r * ldc + c] = v;
      }
    }
  }
}

// ---------------- depthwise causal conv (k=4, left pad 3) + SiLU ----------------
__global__ __launch_bounds__(256) void conv_silu_kernel(
    const float* __restrict__ xi, const float* __restrict__ Wc,
    const float* __restrict__ bc, float* __restrict__ xc) {
  int idx = blockIdx.x * blockDim.x + threadIdx.x;   // over M_SZ*DI
  if (idx >= M_SZ * DI) return;
  int d  = idx & (DI - 1);
  int bl = idx >> 11;            // row (b*L + l)
  int l  = bl & (L_SZ - 1);
  float4 w = ((const float4*)Wc)[d];
  const float* base = xi + (size_t)bl * DI + d;
  float s = bc[d] + base[0] * w.w;
  if (l >= 1) s = fmaf(base[-DI],     w.z, s);
  if (l >= 2) s = fmaf(base[-2 * DI], w.y, s);
  if (l >= 3) s = fmaf(base[-3 * DI], w.x, s);
  float sig = 1.f / (1.f + expf(-s));
  xc[idx] = s * sig;
}

// ---------------- W_B/W_C -> WbcT[64][2048] bf16 hi/lo (interleaved cols, zero-padded) ----------------
__global__ __launch_bounds__(256) void prep_wbc(
    const float* __restrict__ WB, const float* __restrict__ WC,
    unsigned short* __restrict__ Wh, unsigned short* __restrict__ Wl) {
  int idx = blockIdx.x * 256 + threadIdx.x;   // 64*2048
  int c = idx >> 11, k = idx & 2047;
  float v = 0.f;
  if (c < 32) {
    const float* W = (c & 1) ? WC : WB;
    v = W[k * DS + (c >> 1)];
  }
  unsigned short h = rne16(v);
  Wh[idx] = h;
  Wl[idx] = rne16(v - frombf(h));
}

// ---------------- MFMA B/C projection (r6-proven): parts[kz] = xc @ WbcT^T ----------------
__global__ __launch_bounds__(256, 3) void gemm_bcf(
    const float* __restrict__ Af, int lda,
    const unsigned short* __restrict__ Bh, const unsigned short* __restrict__ Bl, int ldb,
    float* __restrict__ parts, int ldc, int Kslice) {
  __shared__ unsigned int AhS[128 * LDF];
  __shared__ unsigned int AlS[128 * LDF];
  __shared__ unsigned int BhS[64 * LDF];
  __shared__ unsigned int BlS[64 * LDF];
  const int tid  = threadIdx.x;
  const int lane = tid & 63, wave = tid >> 6;
  const int wr = wave >> 1, wc = wave & 1;
  const int lm = lane & 15, lq = lane >> 4;
  const int row0 = blockIdx.y * 128;
  const int kbase = blockIdx.x * Kslice;
  float* Cp = parts + (size_t)blockIdx.x * M_SZ * 64;

  f32x4 acc[4][2];
  #pragma unroll
  for (int i = 0; i < 4; ++i)
    #pragma unroll
    for (int j = 0; j < 2; ++j) acc[i][j] = (f32x4){0.f, 0.f, 0.f, 0.f};

  for (int k0 = kbase; k0 < kbase + Kslice; k0 += 32) {
    __syncthreads();
    // A: 128 rows x 32 k fp32 -> hi/lo bf16 in LDS
    #pragma unroll
    for (int i = 0; i < 4; ++i) {
      int idx = tid + i * 256, r = idx >> 3, q = idx & 7;
      float4 v = *(const float4*)(Af + (size_t)(row0 + r) * lda + k0 + q * 4);
      unsigned short h0 = rne16(v.x), h1 = rne16(v.y), h2 = rne16(v.z), h3 = rne16(v.w);
      AhS[r * LDF + q * 2]     = (unsigned)h0 | ((unsigned)h1 << 16);
      AhS[r * LDF + q * 2 + 1] = (unsigned)h2 | ((unsigned)h3 << 16);
      unsigned short l0 = rne16(v.x - frombf(h0)), l1 = rne16(v.y - frombf(h1));
      unsigned short l2 = rne16(v.z - frombf(h2)), l3 = rne16(v.w - frombf(h3));
      AlS[r * LDF + q * 2]     = (unsigned)l0 | ((unsigned)l1 << 16);
      AlS[r * LDF + q * 2 + 1] = (unsigned)l2 | ((unsigned)l3 << 16);
    }
    // B: 64 rows x 32 k bf16 (hi+lo)
    {
      int r = tid >> 2, q = tid & 3;
      size_t go = (size_t)r * ldb + k0 + q * 8;
      *(uint4*)&BhS[r * LDF + q * 4] = *(const uint4*)(Bh + go);
      *(uint4*)&BlS[r * LDF + q * 4] = *(const uint4*)(Bl + go);
    }
    __syncthreads();
    bf16x8 bh[2], bl[2];
    #pragma unroll
    for (int j = 0; j < 2; ++j) {
      bh[j] = *(const bf16x8*)&BhS[(wc * 32 + j * 16 + lm) * LDF + lq * 4];
      bl[j] = *(const bf16x8*)&BlS[(wc * 32 + j * 16 + lm) * LDF + lq * 4];
    }
    #pragma unroll
    for (int i = 0; i < 4; ++i) {
      bf16x8 ah = *(const bf16x8*)&AhS[(wr * 64 + i * 16 + lm) * LDF + lq * 4];
      bf16x8 al = *(const bf16x8*)&AlS[(wr * 64 + i * 16 + lm) * LDF + lq * 4];
      #pragma unroll
      for (int j = 0; j < 2; ++j) {
        acc[i][j] = __builtin_amdgcn_mfma_f32_16x16x32_bf16(ah, bh[j], acc[i][j], 0, 0, 0);
        acc[i][j] = __builtin_amdgcn_mfma_f32_16x16x32_bf16(ah, bl[j], acc[i][j], 0, 0, 0);
        acc[i][j] = __builtin_amdgcn_mfma_f32_16x16x32_bf16(al, bh[j], acc[i][j], 0, 0, 0);
      }
    }
  }
  #pragma unroll
  for (int i = 0; i < 4; ++i) {
    #pragma unroll
    for (int j = 0; j < 2; ++j) {
      int c = wc * 32 + j * 16 + lm;
      #pragma unroll
      for (int k = 0; k < 4; ++k) {
        int r = row0 + wr * 64 + i * 16 + lq * 4 + k;
        Cp[(size_t)r * ldc + c] = acc[i][j][k];
      }
    }
  }
}

// ---------------- sum K-split partials + bias -> BCm2 (stride 64) + Bs (row-contiguous B) ----------------
// Bs[row*16 + s]: 64B-contiguous B row for scan_maps2's float4 broadcast loads.
__global__ __launch_bounds__(256) void prep_bc_sum(
    const float* __restrict__ parts,
    const float* __restrict__ bB, const float* __restrict__ bC,
    float* __restrict__ BCm2, float* __restrict__ Bs) {
  int idx = blockIdx.x * 256 + threadIdx.x;   // M_SZ * 32
  int row = idx >> 5, c = idx & 31;
  float s = 0.f;
  #pragma unroll
  for (int kz = 0; kz < KZN; ++kz)
    s += parts[(size_t)kz * M_SZ * 64 + (size_t)row * 64 + c];
  s += (c & 1) ? bC[c >> 1] : bB[c >> 1];
  BCm2[(size_t)row * 64 + c] = s;
  if (!(c & 1))
    Bs[(size_t)row * 16 + (c >> 1)] = s;
}

// ---------------- selective scan ----------------
__device__ __forceinline__ float clampA(float a) {
  return fminf(fmaxf(a, -10.f), 2.f);
}

// ---- pass 1 v4: parallel composed clamped-affine maps, CHANNEL-MAJOR access ----
// r7 post-mortem: the map algebra passed validation, but the (seg,s)-thread
// layout made every x load touch 64 rows 512KB apart (64 lines/instr) -> TA
// serialization, 383us at 67GB/s. v4 keeps the EXACT r7 compose/middle math
// (bitwise) and restructures access like pass2:
//   block = (b, 8-d group), 256 threads = 8 dloc x 32 seg
//   per thread: compose the 64-step map of (d, seg) for all 16 states in regs
//   x loads: lane-adjacent d -> 32B chunks (8 lines/instr, was 64)
//   B loads: Bs[row][16] -> 4 float4, 8-way lane broadcast
//   maps -> 64KB LDS LM[s][seg][dloc] -> 1 sync -> 128-thread middle scan -> hseg
__global__ __launch_bounds__(256, 2) void scan_maps2(
    const float* __restrict__ xc, const float* __restrict__ Bs,
    const float* __restrict__ A_log, float* __restrict__ hseg) {
  // XCD-bijective swizzle: line-sharing adjacent d-groups land on one XCD
  const int gx  = (blockIdx.x & 7) * 32 + (blockIdx.x >> 3);  // 0..255
  const int b   = blockIdx.y;
  const int tid = threadIdx.x;
  const int dloc = tid & 7;        // channel within group
  const int seg  = tid >> 3;       // 0..31
  const int d    = gx * 8 + dloc;

  float Av[16];
  #pragma unroll
  for (int q = 0; q < 4; ++q) {
    float4 al = *(const float4*)(A_log + d * DS + q * 4);
    Av[q * 4 + 0] = -expf(clampA(al.x));
    Av[q * 4 + 1] = -expf(clampA(al.y));
    Av[q * 4 + 2] = -expf(clampA(al.z));
    Av[q * 4 + 3] = -expf(clampA(al.w));
  }

  const float* px  = xc + ((size_t)b * L_SZ + seg * SEGLEN) * DI + d;
  const float* pbs = Bs + ((size_t)b * L_SZ + seg * SEGLEN) * 16;

  float a[16], bb[16], lo[16], hi[16];
  {
    // step 0 init: h -> clamp(A h + u0, -100, 100)
    const float x = px[0];
    float4 B0 = *(const float4*)(pbs + 0),  B1 = *(const float4*)(pbs + 4);
    float4 B2 = *(const float4*)(pbs + 8),  B3 = *(const float4*)(pbs + 12);
    float Bv[16] = {B0.x,B0.y,B0.z,B0.w, B1.x,B1.y,B1.z,B1.w,
                    B2.x,B2.y,B2.z,B2.w, B3.x,B3.y,B3.z,B3.w};
    #pragma unroll
    for (int s = 0; s < 16; ++s) {
      a[s] = Av[s]; bb[s] = x * Bv[s]; lo[s] = -100.f; hi[s] = 100.f;
    }
  }
  #pragma unroll 2
  for (int t = 1; t < SEGLEN; ++t) {
    const float x = px[t * DI];
    const float* bp = pbs + t * 16;
    float4 B0 = *(const float4*)(bp + 0),  B1 = *(const float4*)(bp + 4);
    float4 B2 = *(const float4*)(bp + 8),  B3 = *(const float4*)(bp + 12);
    float Bv[16] = {B0.x,B0.y,B0.z,B0.w, B1.x,B1.y,B1.z,B1.w,
                    B2.x,B2.y,B2.z,B2.w, B3.x,B3.y,B3.z,B3.w};
    #pragma unroll
    for (int s = 0; s < 16; ++s) {
      const float uu = x * Bv[s];
      const float A  = Av[s];
      float nb = fmaf(A, bb[s], uu);
      float nl = __builtin_amdgcn_fmed3f(fmaf(A, hi[s], uu), -100.f, 100.f);
      float nh = __builtin_amdgcn_fmed3f(fmaf(A, lo[s], uu), -100.f, 100.f);
      a[s] *= A; bb[s] = nb; lo[s] = nl; hi[s] = nh;
    }
  }

  // sanitize overflow (a/bb may run to +-inf when |A|>1; r7-proven)
  __shared__ float4 LM[DS][SEGS][8];   // [s][seg][dloc] = 64 KB
  #pragma unroll
  for (int s = 0; s < 16; ++s) {
    float as = __builtin_amdgcn_fmed3f(a[s],  -1e30f, 1e30f);
    float bs = __builtin_amdgcn_fmed3f(bb[s], -1e30f, 1e30f);
    LM[s][seg][dloc] = make_float4(as, bs, lo[s], hi[s]);
  }
  __syncthreads();

  // middle scan: 128 threads (8 dloc x 16 s) walk 31 maps, emit boundary states
  if (tid < 128) {
    const int dl2 = tid & 7, s2 = tid >> 3;
    const int d2  = gx * 8 + dl2;
    float h = 0.f;
    #pragma unroll
    for (int k = 0; k < SEGS - 1; ++k) {
      float4 m = LM[s2][k][dl2];
      h = __builtin_amdgcn_fmed3f(fmaf(m.x, h, m.y), m.z, m.w);
      hseg[(((size_t)b * (SEGS - 1) + k) * DI + d2) * DS + s2] = h;
    }
  }
}

// ---- pass 2: channel-major, h[16]/A[16] in registers, zero cross-lane (r4/r6-proven) ----
__global__ __launch_bounds__(256, 2) void scan_pass2(
    const float* __restrict__ xc, const float* __restrict__ BCm2,
    const unsigned short* __restrict__ zb,
    const float* __restrict__ A_log, const float* __restrict__ Dv,
    const float* __restrict__ hseg, unsigned short* __restrict__ yg) {
  const int b   = blockIdx.y >> 5;        // SEGS = 32
  const int seg = blockIdx.y & 31;
  const int d   = blockIdx.x * 256 + threadIdx.x;

  float A[16], h[16];
  #pragma unroll
  for (int q = 0; q < 4; ++q) {
    float4 al = *(const float4*)(A_log + d * DS + q * 4);
    A[q * 4 + 0] = -expf(clampA(al.x));
    A[q * 4 + 1] = -expf(clampA(al.y));
    A[q * 4 + 2] = -expf(clampA(al.z));
    A[q * 4 + 3] = -expf(clampA(al.w));
  }
  const float Dr = Dv[d];
  if (seg == 0) {
    #pragma unroll
    for (int s = 0; s < 16; ++s) h[s] = 0.f;
  } else {
    const float* hp = hseg + (((size_t)b * (SEGS - 1) + seg - 1) * DI + d) * DS;
    #pragma unroll
    for (int q = 0; q < 4; ++q) {
      float4 hv = *(const float4*)(hp + q * 4);
      h[q * 4 + 0] = hv.x; h[q * 4 + 1] = hv.y;
      h[q * 4 + 2] = hv.z; h[q * 4 + 3] = hv.w;
    }
  }

  const int rbase = b * L_SZ + seg * SEGLEN;
  const float*          px  = xc  + (size_t)rbase * DI + d;
  const unsigned short* pz  = zb  + (size_t)rbase * DI + d;
  unsigned short*       py  = yg  + (size_t)rbase * DI + d;
  const float*          pbc = BCm2 + (size_t)rbase * 64;

  #pragma unroll 2
  for (int t = 0; t < SEGLEN; ++t) {
    const float x = px[t * DI];
    const float* bc = pbc + t * 64;   // wave-uniform address
    float y = Dr * x;
    #pragma unroll
    for (int s = 0; s < 16; ++s) {
      h[s] = __builtin_amdgcn_fmed3f(fmaf(h[s], A[s], x * bc[s * 2]), -100.f, 100.f);
      y = fmaf(h[s], bc[s * 2 + 1], y);
    }
    y = __builtin_amdgcn_fmed3f(y, -100.f, 100.f);
    const float zf = frombf(pz[t * DI]);
    py[t * DI] = rne16(y * (1.f / (1.f + expf(-zf))));
  }
}

// ---------------- launch ----------------
// ws layout (bytes), peak 88.6 MB:
//   [0,        16777216)  yg bf16 (after conv; region was xi fp32 GEMM1 out)
//   [16777216, 25165824)  parts fp32 (gemm_bcf partials, 8 MB; dead after
//                          prep_bc_sum) -- then hseg fp32 [16777216, 24903680)
//   [25165824, 26214400)  BCm2 fp32 stride-64 {B,C} (1 MB)
//   [26214400, 26476544)  Bs fp32 row-contiguous B (256 KB)
//   [0,        33554432)  xi fp32 before conv (GEMM1 out, conv in)
//   [33554432, 50331648)  z bf16
//   [50331648, 83886080)  xc fp32 (conv out); BEFORE conv hosts xh/xl/WhT/WlT
//   [83886080, 84410368)  WbcT bf16 hi+lo (512 KB)
//   [84410368, 88604672)  WoutT bf16
extern "C" void kernel_launch(void* const* d_in, const int* in_sizes, int n_in,
                              void* d_out, int out_size, void* d_ws, size_t ws_size,
                              hipStream_t stream) {
  const float* x      = (const float*)d_in[0];
  const float* W_in   = (const float*)d_in[1];
  const float* b_in   = (const float*)d_in[2];
  const float* W_conv = (const float*)d_in[3];
  const float* b_conv = (const float*)d_in[4];
  const float* A_log  = (const float*)d_in[5];
  const float* Dv     = (const float*)d_in[6];
  const float* W_B    = (const float*)d_in[7];
  const float* b_B    = (const float*)d_in[8];
  const float* W_C    = (const float*)d_in[9];
  const float* b_C    = (const float*)d_in[10];
  const float* W_out  = (const float*)d_in[11];
  const float* b_out  = (const float*)d_in[12];
  float* out = (float*)d_out;

  char* w = (char*)d_ws;
  float*          xi    = (float*)(w + 0);
  unsigned short* yg    = (unsigned short*)(w + 0);          // reuse after conv
  float*          parts = (float*)(w + 16777216);            // dead-xi zone
  float*          hseg  = (float*)(w + 16777216);            // after parts die
  float*          BCm2  = (float*)(w + 25165824);
  float*          Bs    = (float*)(w + 26214400);
  unsigned short* zb    = (unsigned short*)(w + 33554432);
  float*          xc    = (float*)(w + 50331648);
  unsigned short* xh    = (unsigned short*)(w + 50331648);   // pre-conv phase
  unsigned short* xl    = (unsigned short*)(w + 58720256);
  unsigned short* WhT   = (unsigned short*)(w + 67108864);
  unsigned short* WlT   = (unsigned short*)(w + 75497472);
  unsigned short* WbcTh = (unsigned short*)(w + 83886080);
  unsigned short* WbcTl = (unsigned short*)(w + 84148224);
  unsigned short* WoT   = (unsigned short*)(w + 84410368);

  // 0a) x -> xh/xl
  convert_x<<<M_SZ * DM / 1024, 256, 0, stream>>>(x, xh, xl);
  // 0b) W_in (DM x N_XZ) -> WhT/WlT (N_XZ x DM)
  transpose_w<<<dim3(N_XZ / 64, DM / 64), 256, 0, stream>>>(W_in, DM, N_XZ, WhT, WlT);
  // 0c) W_out (DI x DM) -> WoT (DM x DI), hi only (post-scan path)
  transpose_w<<<dim3(DM / 64, DI / 64), 256, 0, stream>>>(W_out, DI, DM, WoT, nullptr);
  // 0d) W_B/W_C -> WbcT hi/lo
  prep_wbc<<<64 * 2048 / 256, 256, 0, stream>>>(W_B, W_C, WbcTh, WbcTl);

  // 1a) xi = x @ W_in[:, :DI] + b_in[:DI]  -- bf16x3 (scan-sensitive), fp32 out
  gemm_t<128, true, false><<<dim3(DI / 128, M_SZ / 128), 256, 0, stream>>>(
      xh, xl, DM, WhT, WlT, DM, b_in, xi, nullptr, DI, DM);

  // 1b) z = x @ W_in[:, DI:] + b_in[DI:]  -- plain bf16 (gate path), bf16 out
  gemm_t<128, false, true><<<dim3(DI / 128, M_SZ / 128), 256, 0, stream>>>(
      xh, nullptr, DM, WhT + (size_t)DI * DM, nullptr, DM,
      b_in + DI, nullptr, zb, DI, DM);

  // 2) xc = silu(causal_dwconv(xi) + b_conv)
  conv_silu_kernel<<<M_SZ * DI / 256, 256, 0, stream>>>(xi, W_conv, b_conv, xc);

  // 3a) B/C projection partials via MFMA (K-split 8, full chip)
  gemm_bcf<<<dim3(KZN, M_SZ / 128), 256, 0, stream>>>(
      xc, DI, WbcTh, WbcTl, DI, parts, 64, DI / KZN);
  // 3b) sum partials + bias -> BCm2 + Bs
  prep_bc_sum<<<M_SZ * 32 / 256, 256, 0, stream>>>(parts, b_B, b_C, BCm2, Bs);

  // 4a) pass1 v4: channel-major composed maps -> 31 boundary states
  scan_maps2<<<dim3(DI / 8, B_SZ), 256, 0, stream>>>(xc, Bs, A_log, hseg);

  // 4b) pass2: 32 parallel 64-step segments -> yg bf16
  scan_pass2<<<dim3(DI / 256, B_SZ * SEGS), 256, 0, stream>>>(
      xc, BCm2, zb, A_log, Dv, hseg, yg);

  // 5) out = yg @ W_out + b_out, pure bf16 MFMA (BN=64)
  gemm_t<64, false, false><<<dim3(DM / 64, M_SZ / 128), 256, 0, stream>>>(
      yg, nullptr, DI, WoT, nullptr, DI, b_out, out, nullptr, DM, DI);
}